// Round 1
// baseline (560.468 us; speedup 1.0000x reference)
//
#include <hip/hip_runtime.h>
#include <hip/hip_bf16.h>

// GraphLayer B=8,N=2048,D=512 — Round 5.
//   r4 post-mortem: scores 107us (MfmaUtil 12%, HBM 24% — latency-bound),
//   agg re-reads the 67MB Wbf intermediate. Nothing saturated.
//   Changes:
//   1) FUSE scores+agg into attn_kernel (flash-style): per block 64 q-rows x
//      D=512, loop over 128-wide k-tiles: S=QK^T (fp16 MFMA) -> P=bf16(adj*exp)
//      staged in LDS -> acc += P*V^T (bf16 MFMA). Wbf never materialized.
//   2) den: per-lane fp32 sums of the SAME bf16-rounded P values (cancellation
//      preserved), one shfl_xor butterfly at kernel end. Deletes den-MFMA
//      (+25% matrix-pipe in old agg).
//   3) XOR-granule LDS swizzle on ALL stagings (pre-swizzled global source +
//      swizzled ds_read; LDS dest linear per global_load_lds constraint):
//      8-way -> 2-way bank conflicts. Also applied to proj mainloop.
// Numerics: fp16 Q/K path (r3-verified, absmax 0.0156), P/V bf16 (P ~1e13,
// must be bf16), fp32 accum everywhere, den from rounded P.

#define BATCH 8
#define SEQ   2048
#define DIM   512
#define MSEQ  (BATCH * SEQ)   // 16384
#define QB    64              // q-rows per attn block
#define KT    128             // k-tile width

typedef __attribute__((ext_vector_type(8))) short    bf16x8;
typedef __attribute__((ext_vector_type(8))) _Float16 f16x8;
typedef __attribute__((ext_vector_type(4))) float    f32x4;

__device__ __forceinline__ unsigned short f2bf(float f) {
  __hip_bfloat16 h = __float2bfloat16(f);
  union { __hip_bfloat16 h; unsigned short u; } c; c.h = h; return c.u;
}
__device__ __forceinline__ float bf2f(unsigned short u) {
  union { unsigned int u; float f; } c; c.u = ((unsigned int)u) << 16; return c.f;
}
__device__ __forceinline__ unsigned short f2h(float f) {
  union { _Float16 h; unsigned short u; } c; c.h = (_Float16)f; return c.u;
}

__device__ __forceinline__ void async16(const unsigned short* g, unsigned short* l) {
  __builtin_amdgcn_global_load_lds(
      (const __attribute__((address_space(1))) void*)g,
      (__attribute__((address_space(3))) void*)l, 16, 0, 0);
}

// ---------------------------------------------------------------- core ----
// acc[i][j] += A[m][k] * B[n][k]  (NT), fp16 MFMA, fp32 acc. 256 threads.
// LDS rows 32 ushorts (64B, 4 granules); XOR-swizzled granules (2-way banks).
__device__ __forceinline__ void gemm_f16_mainloop(
    const unsigned short* __restrict__ A, const unsigned short* __restrict__ B,
    int lda, int ldb, int K,
    unsigned short* sA, unsigned short* sB, f32x4 acc[4][4])
{
  const int tid  = threadIdx.x;
  const int lane = tid & 63;
  const int w    = tid >> 6;
  const int wm   = w >> 1, wn = w & 1;
  const int quad = lane >> 4, fcol = lane & 15;
  const int srow = lane >> 2;          // 0..15 within a 16-row chunk
  // swizzled source granule: f(r) = (r&3) ^ ((r>>2)&3), r low-4 == srow
  const int gsw  = ((lane & 3) ^ ((srow & 3) ^ ((srow >> 2) & 3))) * 8;
  // read-side granule swizzle depends only on fcol (rows = ..*16 + fcol)
  const int grd  = ((fcol & 3) ^ ((fcol >> 2) & 3));

  for (int k0 = 0; k0 < K; k0 += 32) {
#pragma unroll
    for (int inst = 0; inst < 2; ++inst) {
      const int rbase  = w * 32 + inst * 16;   // wave-uniform
      const int r      = rbase + srow;
      const int ldsoff = rbase * 32;           // row stride 32 ushorts
      async16(A + (size_t)r * lda + k0 + gsw, sA + ldsoff);
      async16(B + (size_t)r * ldb + k0 + gsw, sB + ldsoff);
    }
    __syncthreads();

#pragma unroll
    for (int i = 0; i < 4; ++i) {
      const int ar = wm * 64 + i * 16 + fcol;
      f16x8 a = *(const f16x8*)(sA + ar * 32 + ((quad ^ grd) << 3));
#pragma unroll
      for (int j = 0; j < 4; ++j) {
        const int br = wn * 64 + j * 16 + fcol;
        f16x8 b = *(const f16x8*)(sB + br * 32 + ((quad ^ grd) << 3));
        acc[i][j] = __builtin_amdgcn_mfma_f32_16x16x32_f16(a, b, acc[i][j], 0, 0, 0);
      }
    }
    __syncthreads();
  }
}

#define EPI_SETUP                                                  \
  const int lane = threadIdx.x & 63;                               \
  const int w_   = threadIdx.x >> 6;                               \
  const int wm   = w_ >> 1, wn = w_ & 1;                           \
  const int quad = lane >> 4, fcol = lane & 15;

// ----------------------------------------------------------------- cvt ----
__global__ __launch_bounds__(256) void cvt_kernel(
    const float* __restrict__ in, unsigned short* __restrict__ out, int n4)
{
  int i = blockIdx.x * 256 + threadIdx.x;
  if (i >= n4) return;
  float4 v = ((const float4*)in)[i];
  ushort4 h;
  h.x = f2h(v.x); h.y = f2h(v.y); h.z = f2h(v.z); h.w = f2h(v.w);
  ((ushort4*)out)[i] = h;
}

__global__ __launch_bounds__(256) void cvt_w_kernel(
    const float* __restrict__ w0, const float* __restrict__ w1,
    const float* __restrict__ w2, unsigned short* __restrict__ o0,
    unsigned short* __restrict__ o1, unsigned short* __restrict__ o2, int n4)
{
  int i = blockIdx.x * 256 + threadIdx.x;
  if (i >= n4) return;
  const float* in = (blockIdx.y == 0) ? w0 : (blockIdx.y == 1) ? w1 : w2;
  unsigned short* out = (blockIdx.y == 0) ? o0 : (blockIdx.y == 1) ? o1 : o2;
  float4 v = ((const float4*)in)[i];
  ushort4 h;
  h.x = f2h(v.x); h.y = f2h(v.y); h.z = f2h(v.z); h.w = f2h(v.w);
  ((ushort4*)out)[i] = h;
}

// ------------------------------------------------------------- proj QK ----
__global__ __launch_bounds__(256) void proj_qk_kernel(
    const unsigned short* __restrict__ xh,
    const unsigned short* __restrict__ wq, const unsigned short* __restrict__ wk,
    const float* __restrict__ bq, const float* __restrict__ bk,
    unsigned short* __restrict__ Qh, unsigned short* __restrict__ Kh)
{
  __shared__ unsigned short sA[128 * 32], sB[128 * 32];
  const unsigned short* wh = blockIdx.z ? wk : wq;
  const float* bias        = blockIdx.z ? bk : bq;
  unsigned short* O        = blockIdx.z ? Kh : Qh;
  const int m0 = blockIdx.y * 128, n0 = blockIdx.x * 128;
  f32x4 acc[4][4];
#pragma unroll
  for (int i = 0; i < 4; ++i)
#pragma unroll
    for (int j = 0; j < 4; ++j) acc[i][j] = (f32x4){0.f, 0.f, 0.f, 0.f};

  gemm_f16_mainloop(xh + (size_t)m0 * DIM, wh + (size_t)n0 * DIM,
                    DIM, DIM, DIM, sA, sB, acc);
  EPI_SETUP
#pragma unroll
  for (int i = 0; i < 4; ++i)
#pragma unroll
    for (int j = 0; j < 4; ++j)
#pragma unroll
      for (int r = 0; r < 4; ++r) {
        const int row = m0 + wm * 64 + i * 16 + quad * 4 + r;
        const int col = n0 + wn * 64 + j * 16 + fcol;
        O[(size_t)row * DIM + col] = f2h(acc[i][j][r] + bias[col]);
      }
}

// -------------------------------------------------------------- proj V ----
// Vt[d][m] = Wv[d][:] . x[m][:] + bv[d]   (fp16 in, bf16 out, transposed)
__global__ __launch_bounds__(256) void proj_v_kernel(
    const unsigned short* __restrict__ wvh, const unsigned short* __restrict__ xh,
    const float* __restrict__ bias, unsigned short* __restrict__ Vt)
{
  __shared__ unsigned short sA[128 * 32], sB[128 * 32];
  const int m0 = blockIdx.y * 128, n0 = blockIdx.x * 128;
  f32x4 acc[4][4];
#pragma unroll
  for (int i = 0; i < 4; ++i)
#pragma unroll
    for (int j = 0; j < 4; ++j) acc[i][j] = (f32x4){0.f, 0.f, 0.f, 0.f};

  gemm_f16_mainloop(wvh + (size_t)m0 * DIM, xh + (size_t)n0 * DIM,
                    DIM, DIM, DIM, sA, sB, acc);
  EPI_SETUP
#pragma unroll
  for (int i = 0; i < 4; ++i)
#pragma unroll
    for (int j = 0; j < 4; ++j)
#pragma unroll
      for (int r = 0; r < 4; ++r) {
        const int row = m0 + wm * 64 + i * 16 + quad * 4 + r;   // d
        const int col = n0 + wn * 64 + j * 16 + fcol;           // seq
        Vt[(size_t)row * MSEQ + col] = f2bf(acc[i][j][r] + bias[row]);
      }
}

// ---------------------------------------------------------------- attn ----
// Fused scores+agg. Block: 64 q-rows x D=512, 512 threads (8 waves).
// Per 128-wide k-tile:
//   phase1: S[64x128] = Q.K^T (fp16 MFMA, BK=64 steps, staged LDS)
//   epilog: P = bf16(adj*exp(S)) -> swizzled LDS (aliases QK staging);
//           den partials += bf16-rounded P (fp32, per-lane)
//   phase2: acc[64x512] += P.V^T (bf16 MFMA, V staged [512x32]/step)
// End: shfl butterfly den -> LDS -> out = acc/den.
__global__ __launch_bounds__(512, 4) void attn_kernel(
    const unsigned short* __restrict__ Qh, const unsigned short* __restrict__ Kh,
    const unsigned short* __restrict__ Vt, const float* __restrict__ adj,
    float* __restrict__ out)
{
  // LDS arena (56 KB): [0,12288) ushorts Qs[64][64]+Ks[128][64], aliased by
  // P[64][128]; [12288,28672) Vs[512][32], aliased by denL[4][64] floats.
  __shared__ __align__(16) unsigned short smem[28672];
  unsigned short* Qs = smem;                 // row stride 64 ushorts
  unsigned short* Ks = smem + 64 * 64;       // row stride 64 ushorts
  unsigned short* Pb = smem;                 // row stride 128 ushorts (bf16)
  unsigned short* Vs = smem + 12288;         // row stride 32 ushorts

  const int tid  = threadIdx.x;
  const int lane = tid & 63;
  const int w    = tid >> 6;                 // 0..7
  const int quad = lane >> 4, fcol = lane & 15;
  const int wq = w >> 2, wk = w & 3;         // phase-1 wave grid 2x4 (32q x 32k)

  const int b  = blockIdx.y;
  const int q0 = blockIdx.x * QB;
  const size_t qbase = (size_t)b * SEQ + q0;
  const float* adjb = adj + ((size_t)b * SEQ + q0) * SEQ;
  const unsigned short* Vb = Vt + (size_t)b * SEQ;

  // staging lane constants
  const int srow8 = lane >> 3;                       // QK staging (8 granules/row)
  const int g8    = ((lane & 7) ^ (srow8 & 7)) * 8;  // swizzled src granule
  const int srow4 = lane >> 2;                       // V staging (4 granules/row)
  // read-side V granule swizzle: rows = ..*16 + fcol -> depends only on fcol
  const int gv    = ((fcol & 3) ^ ((fcol >> 2) & 3));

  f32x4 acc[4][4];
#pragma unroll
  for (int i = 0; i < 4; ++i)
#pragma unroll
    for (int j = 0; j < 4; ++j) acc[i][j] = (f32x4){0.f, 0.f, 0.f, 0.f};
  float den[2][4];
#pragma unroll
  for (int i = 0; i < 2; ++i)
#pragma unroll
    for (int r = 0; r < 4; ++r) den[i][r] = 0.f;

  for (int k0 = 0; k0 < SEQ; k0 += KT) {
    // ----------------- phase 1: S = Q.K^T over D=512 -----------------
    f32x4 sacc[2][2];
#pragma unroll
    for (int i = 0; i < 2; ++i)
#pragma unroll
      for (int j = 0; j < 2; ++j) sacc[i][j] = (f32x4){0.f, 0.f, 0.f, 0.f};

    const size_t kbase = (size_t)b * SEQ + k0;
    for (int kk = 0; kk < DIM; kk += 64) {   // 8 steps
      {  // Q: rows w*8..+8, one 1KB call
        const int r = w * 8 + srow8;
        async16(Qh + (qbase + r) * DIM + kk + g8, Qs + w * 8 * 64);
      }
#pragma unroll
      for (int inst = 0; inst < 2; ++inst) { // K: rows w*16..+16
        const int r = w * 16 + inst * 8 + srow8;
        async16(Kh + (kbase + r) * DIM + kk + g8, Ks + (w * 16 + inst * 8) * 64);
      }
      __syncthreads();
#pragma unroll
      for (int ks = 0; ks < 2; ++ks) {
        f16x8 a[2], bb[2];
#pragma unroll
        for (int i = 0; i < 2; ++i) {
          const int ar = wq * 32 + i * 16 + fcol;
          a[i] = *(const f16x8*)(Qs + ar * 64 + (((quad + ks * 4) ^ (ar & 7)) << 3));
        }
#pragma unroll
        for (int j = 0; j < 2; ++j) {
          const int br = wk * 32 + j * 16 + fcol;
          bb[j] = *(const f16x8*)(Ks + br * 64 + (((quad + ks * 4) ^ (br & 7)) << 3));
        }
#pragma unroll
        for (int i = 0; i < 2; ++i)
#pragma unroll
          for (int j = 0; j < 2; ++j)
            sacc[i][j] = __builtin_amdgcn_mfma_f32_16x16x32_f16(a[i], bb[j], sacc[i][j], 0, 0, 0);
      }
      __syncthreads();
    }

    // --------- epilogue: P = bf16(adj*exp(S)) -> LDS; den += P -------
#pragma unroll
    for (int i = 0; i < 2; ++i) {
      const int row = wq * 32 + i * 16 + quad * 4;
#pragma unroll
      for (int j = 0; j < 2; ++j) {
        const int col = wk * 32 + j * 16 + fcol;
#pragma unroll
        for (int r = 0; r < 4; ++r) {
          const float aval = adjb[(size_t)(row + r) * SEQ + k0 + col];
          const unsigned short pb = f2bf(aval * __expf(sacc[i][j][r]));
          Pb[(row + r) * 128 + ((((col >> 3) ^ ((row + r) & 7)) << 3) | (col & 7))] = pb;
          den[i][r] += bf2f(pb);
        }
      }
    }
    __syncthreads();

    // ----------------- phase 2: acc += P . V^T -----------------------
#pragma unroll
    for (int ks = 0; ks < 4; ++ks) {
#pragma unroll
      for (int c = 0; c < 4; ++c) {          // V rows w*64..+64 (4x 1KB calls)
        const int rv = w * 64 + c * 16 + srow4;
        const int gs = (lane & 3) ^ ((rv & 3) ^ ((rv >> 2) & 3));
        async16(Vb + (size_t)rv * MSEQ + k0 + ks * 32 + gs * 8,
                Vs + (w * 64 + c * 16) * 32);
      }
      __syncthreads();
#pragma unroll
      for (int i = 0; i < 4; ++i) {
        const int ar = i * 16 + fcol;
        bf16x8 a = *(const bf16x8*)(Pb + ar * 128 + (((ks * 4 + quad) ^ (ar & 7)) << 3));
#pragma unroll
        for (int j = 0; j < 4; ++j) {
          const int br = w * 64 + j * 16 + fcol;
          bf16x8 bv = *(const bf16x8*)(Vs + br * 32 + ((quad ^ gv) << 3));
          acc[i][j] = __builtin_amdgcn_mfma_f32_16x16x32_bf16(a, bv, acc[i][j], 0, 0, 0);
        }
      }
      __syncthreads();
    }
  }

  // ----------------- den reduce + normalize + store -------------------
  float* denL = (float*)Vs;   // [4 wk][64 rows], safe: loop ended on barrier
#pragma unroll
  for (int i = 0; i < 2; ++i)
#pragma unroll
    for (int r = 0; r < 4; ++r) {
      float v = den[i][r];
      v += __shfl_xor(v, 1);  v += __shfl_xor(v, 2);
      v += __shfl_xor(v, 4);  v += __shfl_xor(v, 8);
      if (fcol == 0) denL[wk * 64 + wq * 32 + i * 16 + quad * 4 + r] = v;
    }
  __syncthreads();
#pragma unroll
  for (int i = 0; i < 4; ++i)
#pragma unroll
    for (int r = 0; r < 4; ++r) {
      const int row = i * 16 + quad * 4 + r;
      const float d = denL[row] + denL[64 + row] + denL[128 + row] + denL[192 + row];
      const float rd = 1.0f / d;
      float* orow = out + (qbase + row) * DIM + w * 64;
#pragma unroll
      for (int j = 0; j < 4; ++j)
        orow[j * 16 + fcol] = acc[i][j][r] * rd;
    }
}

// -------------------------------------------------------------- launch ----
extern "C" void kernel_launch(void* const* d_in, const int* in_sizes, int n_in,
                              void* d_out, int out_size, void* d_ws, size_t ws_size,
                              hipStream_t stream) {
  const float* x   = (const float*)d_in[0];
  const float* adj = (const float*)d_in[1];
  const float* Wq  = (const float*)d_in[2];
  const float* bq  = (const float*)d_in[3];
  const float* Wk  = (const float*)d_in[4];
  const float* bk  = (const float*)d_in[5];
  const float* Wv  = (const float*)d_in[6];
  const float* bv  = (const float*)d_in[7];
  float* out = (float*)d_out;

  const size_t NX = (size_t)MSEQ * DIM;   // 8,388,608
  const size_t NW = (size_t)DIM * DIM;    // 262,144
  unsigned short* ws = (unsigned short*)d_ws;
  unsigned short* xh  = ws;               // fp16
  unsigned short* wqh = xh + NX;
  unsigned short* wkh = wqh + NW;
  unsigned short* wvh = wkh + NW;
  unsigned short* Qh  = wvh + NW;         // fp16
  unsigned short* Kh  = Qh + NX;          // fp16
  unsigned short* Vt  = Kh + NX;          // bf16, transposed [DIM][MSEQ]

  // 1. fp32 -> fp16 conversions (2 launches)
  cvt_kernel<<<(int)(NX / 4 / 256), 256, 0, stream>>>(x, xh, (int)(NX / 4));
  dim3 cw((int)(NW / 4 / 256), 3);
  cvt_w_kernel<<<cw, 256, 0, stream>>>(Wq, Wk, Wv, wqh, wkh, wvh, (int)(NW / 4));

  // 2. projections (2 launches)
  dim3 pq(DIM / 128, MSEQ / 128, 2);       // (4, 128, 2) — z: Q or K
  proj_qk_kernel<<<pq, 256, 0, stream>>>(xh, wqh, wkh, bq, bk, Qh, Kh);
  dim3 pv(MSEQ / 128, DIM / 128);          // (128, 4)
  proj_v_kernel<<<pv, 256, 0, stream>>>(wvh, xh, bv, Vt);

  // 3. fused attention (scores+agg)
  dim3 at(SEQ / QB, BATCH);                // (32, 8) = 256 blocks
  attn_kernel<<<at, 512, 0, stream>>>(Qh, Kh, Vt, adj, out);
}